// Round 1
// baseline (4387.928 us; speedup 1.0000x reference)
//
#include <hip/hip_runtime.h>
#include <math.h>

#define NN 100000
#define NEDGE 1600000
#define NTOT 1700000          // edges + self loops
#define FIN 512
#define NH1 8
#define NC1 8
#define F1 64                 // NH1*NC1
#define NC2 10
#define SLOPE 0.2f
#define EPSF 1e-16f

__device__ __forceinline__ float lrelu(float x) { return x > 0.f ? x : SLOPE * x; }
__device__ __forceinline__ float eluf(float x) { return x > 0.f ? x : __expf(x) - 1.f; }

__device__ __forceinline__ void get_edge(const int* __restrict__ ei, int e, int& s, int& d) {
    if (e < NEDGE) { s = ei[e]; d = ei[NEDGE + e]; }
    else { s = e - NEDGE; d = s; }
}

// ---------------- GEMM1: h1[NN,64] = x[NN,512] @ W1[512,64] ----------------
#define BM 64
#define BK 32

__global__ __launch_bounds__(256) void k_gemm1(const float* __restrict__ x,
                                               const float* __restrict__ W,
                                               float* __restrict__ h1)
{
    __shared__ float As[BK][BM + 4];   // x tile stored transposed [k][row], stride 68 (16B-aligned rows, 2-way-free banks)
    __shared__ float Bs[BK][F1 + 4];   // W tile [k][n]
    const int tid = threadIdx.x;
    const int row0 = blockIdx.x * BM;
    const int ti = tid >> 4, tj = tid & 15;
    float acc[4][4] = {};

    for (int k0 = 0; k0 < FIN; k0 += BK) {
        // load x tile: 64 rows x 32 k = 512 float4
        #pragma unroll
        for (int l = 0; l < 2; ++l) {
            int idx = tid + l * 256;
            int r = idx >> 3, c4 = idx & 7;
            int gr = row0 + r;
            float4 v = make_float4(0.f, 0.f, 0.f, 0.f);
            if (gr < NN) v = *(const float4*)(x + (size_t)gr * FIN + k0 + (c4 << 2));
            As[(c4 << 2) + 0][r] = v.x;
            As[(c4 << 2) + 1][r] = v.y;
            As[(c4 << 2) + 2][r] = v.z;
            As[(c4 << 2) + 3][r] = v.w;
        }
        // load W tile: 32 k x 64 n = 512 float4
        #pragma unroll
        for (int l = 0; l < 2; ++l) {
            int idx = tid + l * 256;
            int r = idx >> 4, c4 = idx & 15;
            float4 v = *(const float4*)(W + (size_t)(k0 + r) * F1 + (c4 << 2));
            *(float4*)&Bs[r][c4 << 2] = v;
        }
        __syncthreads();
        #pragma unroll
        for (int kk = 0; kk < BK; ++kk) {
            float4 a = *(const float4*)&As[kk][ti << 2];
            float4 b = *(const float4*)&Bs[kk][tj << 2];
            acc[0][0] += a.x * b.x; acc[0][1] += a.x * b.y; acc[0][2] += a.x * b.z; acc[0][3] += a.x * b.w;
            acc[1][0] += a.y * b.x; acc[1][1] += a.y * b.y; acc[1][2] += a.y * b.z; acc[1][3] += a.y * b.w;
            acc[2][0] += a.z * b.x; acc[2][1] += a.z * b.y; acc[2][2] += a.z * b.z; acc[2][3] += a.z * b.w;
            acc[3][0] += a.w * b.x; acc[3][1] += a.w * b.y; acc[3][2] += a.w * b.z; acc[3][3] += a.w * b.w;
        }
        __syncthreads();
    }
    #pragma unroll
    for (int i = 0; i < 4; ++i) {
        int gr = row0 + (ti << 2) + i;
        if (gr < NN) {
            *(float4*)(h1 + (size_t)gr * F1 + (tj << 2)) =
                make_float4(acc[i][0], acc[i][1], acc[i][2], acc[i][3]);
        }
    }
}

// ---------------- prep1: al1/ar1 [NN,8], d1=0, out1=0 ----------------
__global__ void k_prep1(const float* __restrict__ h1,
                        const float* __restrict__ asrc, const float* __restrict__ adst,
                        float* __restrict__ al, float* __restrict__ ar,
                        float* __restrict__ d1, float* __restrict__ out1)
{
    int i = blockIdx.x * blockDim.x + threadIdx.x;
    if (i < NN * F1) out1[i] = 0.f;
    if (i < NN * NH1) {
        int node = i >> 3, hh = i & 7;
        const float* hp = h1 + (size_t)node * F1 + hh * NC1;
        float4 h0 = *(const float4*)hp;
        float4 h4 = *(const float4*)(hp + 4);
        const float* as = asrc + hh * NC1;
        const float* ad = adst + hh * NC1;
        float sa = h0.x * as[0] + h0.y * as[1] + h0.z * as[2] + h0.w * as[3]
                 + h4.x * as[4] + h4.y * as[5] + h4.z * as[6] + h4.w * as[7];
        float sd = h0.x * ad[0] + h0.y * ad[1] + h0.z * ad[2] + h0.w * ad[3]
                 + h4.x * ad[4] + h4.y * ad[5] + h4.z * ad[6] + h4.w * ad[7];
        al[i] = sa; ar[i] = sd; d1[i] = 0.f;
    }
}

// ---------------- denom1: d1[dst,h] += exp(lrelu(al[src,h]+ar[dst,h])) ----------------
__global__ void k_denom1(const int* __restrict__ ei,
                         const float* __restrict__ al, const float* __restrict__ ar,
                         float* __restrict__ d1)
{
    int i = blockIdx.x * blockDim.x + threadIdx.x;
    if (i >= NTOT * NH1) return;
    int e = i >> 3, hh = i & 7;
    int s, d; get_edge(ei, e, s, d);
    float ev = __expf(lrelu(al[s * NH1 + hh] + ar[d * NH1 + hh]));
    atomicAdd(&d1[d * NH1 + hh], ev);
}

// ---------------- agg1: out1[dst, h*8+c] += h1[src, h*8+c] * alpha ----------------
__global__ void k_agg1(const int* __restrict__ ei,
                       const float* __restrict__ al, const float* __restrict__ ar,
                       const float* __restrict__ d1, const float* __restrict__ h1,
                       float* __restrict__ out1)
{
    int i = blockIdx.x * blockDim.x + threadIdx.x;
    if (i >= NTOT * NH1) return;
    int e = i >> 3, hh = i & 7;
    int s, d; get_edge(ei, e, s, d);
    float ev = __expf(lrelu(al[s * NH1 + hh] + ar[d * NH1 + hh]));
    float alpha = ev / (d1[d * NH1 + hh] + EPSF);
    const float* hp = h1 + (size_t)s * F1 + hh * NC1;
    float4 a0 = *(const float4*)hp;
    float4 a4 = *(const float4*)(hp + 4);
    float* op = out1 + (size_t)d * F1 + hh * NC1;
    atomicAdd(op + 0, a0.x * alpha);
    atomicAdd(op + 1, a0.y * alpha);
    atomicAdd(op + 2, a0.z * alpha);
    atomicAdd(op + 3, a0.w * alpha);
    atomicAdd(op + 4, a4.x * alpha);
    atomicAdd(op + 5, a4.y * alpha);
    atomicAdd(op + 6, a4.z * alpha);
    atomicAdd(op + 7, a4.w * alpha);
}

// ------------- l2prep: g=elu(out1+b1); h2=g@W2; al2/ar2; d2=0; out2=0 -------------
__global__ __launch_bounds__(256) void k_l2prep(
    const float* __restrict__ out1, const float* __restrict__ b1,
    const float* __restrict__ W2, const float* __restrict__ asrc2,
    const float* __restrict__ adst2,
    float* __restrict__ h2, float* __restrict__ al2, float* __restrict__ ar2,
    float* __restrict__ d2, float* __restrict__ out2)
{
    __shared__ float sW[F1 * NC2];
    __shared__ float sb[F1];
    __shared__ float sas[NC2], sad[NC2];
    int tid = threadIdx.x;
    for (int i = tid; i < F1 * NC2; i += 256) sW[i] = W2[i];
    if (tid < F1) sb[tid] = b1[tid];
    if (tid < NC2) { sas[tid] = asrc2[tid]; sad[tid] = adst2[tid]; }
    __syncthreads();
    int n = blockIdx.x * 256 + tid;
    if (n >= NN) return;

    const float* row = out1 + (size_t)n * F1;
    float g[F1];
    #pragma unroll
    for (int c = 0; c < F1; c += 4) {
        float4 v = *(const float4*)(row + c);
        g[c + 0] = eluf(v.x + sb[c + 0]);
        g[c + 1] = eluf(v.y + sb[c + 1]);
        g[c + 2] = eluf(v.z + sb[c + 2]);
        g[c + 3] = eluf(v.w + sb[c + 3]);
    }
    float acc[NC2] = {};
    #pragma unroll
    for (int c = 0; c < F1; ++c) {
        float gc = g[c];
        #pragma unroll
        for (int o = 0; o < NC2; ++o) acc[o] += gc * sW[c * NC2 + o];
    }
    float sa = 0.f, sd = 0.f;
    #pragma unroll
    for (int o = 0; o < NC2; ++o) { sa += acc[o] * sas[o]; sd += acc[o] * sad[o]; }
    al2[n] = sa; ar2[n] = sd; d2[n] = 0.f;
    float* h2p = h2 + (size_t)n * NC2;
    float* o2p = out2 + (size_t)n * NC2;
    #pragma unroll
    for (int o = 0; o < NC2; ++o) { h2p[o] = acc[o]; o2p[o] = 0.f; }
}

// ---------------- denom2 ----------------
__global__ void k_denom2(const int* __restrict__ ei,
                         const float* __restrict__ al2, const float* __restrict__ ar2,
                         float* __restrict__ d2)
{
    int e = blockIdx.x * blockDim.x + threadIdx.x;
    if (e >= NTOT) return;
    int s, d; get_edge(ei, e, s, d);
    atomicAdd(&d2[d], __expf(lrelu(al2[s] + ar2[d])));
}

// ---------------- agg2 ----------------
__global__ void k_agg2(const int* __restrict__ ei,
                       const float* __restrict__ al2, const float* __restrict__ ar2,
                       const float* __restrict__ d2, const float* __restrict__ h2,
                       float* __restrict__ out2)
{
    int e = blockIdx.x * blockDim.x + threadIdx.x;
    if (e >= NTOT) return;
    int s, d; get_edge(ei, e, s, d);
    float alpha = __expf(lrelu(al2[s] + ar2[d])) / (d2[d] + EPSF);
    const float* hp = h2 + (size_t)s * NC2;
    float* op = out2 + (size_t)d * NC2;
    #pragma unroll
    for (int o = 0; o < NC2; ++o) atomicAdd(op + o, hp[o] * alpha);
}

// ---------------- final: out = log_softmax(out2 + b2) ----------------
__global__ void k_final(const float* __restrict__ out2, const float* __restrict__ b2,
                        float* __restrict__ out)
{
    int n = blockIdx.x * blockDim.x + threadIdx.x;
    if (n >= NN) return;
    float z[NC2];
    float m = -1e30f;
    #pragma unroll
    for (int o = 0; o < NC2; ++o) {
        z[o] = out2[(size_t)n * NC2 + o] + b2[o];
        m = fmaxf(m, z[o]);
    }
    float s = 0.f;
    #pragma unroll
    for (int o = 0; o < NC2; ++o) s += __expf(z[o] - m);
    float ls = __logf(s) + m;
    #pragma unroll
    for (int o = 0; o < NC2; ++o) out[(size_t)n * NC2 + o] = z[o] - ls;
}

extern "C" void kernel_launch(void* const* d_in, const int* in_sizes, int n_in,
                              void* d_out, int out_size, void* d_ws, size_t ws_size,
                              hipStream_t stream)
{
    const float* x    = (const float*)d_in[0];
    const int*   ei   = (const int*)d_in[1];
    const float* W1   = (const float*)d_in[2];
    const float* as1  = (const float*)d_in[3];
    const float* ad1  = (const float*)d_in[4];
    const float* b1   = (const float*)d_in[5];
    const float* W2   = (const float*)d_in[6];
    const float* as2  = (const float*)d_in[7];
    const float* ad2  = (const float*)d_in[8];
    const float* b2   = (const float*)d_in[9];
    float* out = (float*)d_out;

    float* ws   = (float*)d_ws;
    float* h1   = ws;                          // NN*64  = 6.4M
    float* al1  = h1  + (size_t)NN * F1;       // NN*8
    float* ar1  = al1 + (size_t)NN * NH1;      // NN*8
    float* d1   = ar1 + (size_t)NN * NH1;      // NN*8
    float* out1 = d1  + (size_t)NN * NH1;      // NN*64
    float* h2   = out1 + (size_t)NN * F1;      // NN*10
    float* al2  = h2  + (size_t)NN * NC2;      // NN
    float* ar2  = al2 + (size_t)NN;            // NN
    float* d2   = ar2 + (size_t)NN;            // NN
    float* out2 = d2  + (size_t)NN;            // NN*10
    // total ~17.5M floats = 70 MB

    k_gemm1<<<(NN + BM - 1) / BM, 256, 0, stream>>>(x, W1, h1);
    k_prep1<<<(NN * F1 + 255) / 256, 256, 0, stream>>>(h1, as1, ad1, al1, ar1, d1, out1);
    int eh = NTOT * NH1;
    k_denom1<<<(eh + 255) / 256, 256, 0, stream>>>(ei, al1, ar1, d1);
    k_agg1<<<(eh + 255) / 256, 256, 0, stream>>>(ei, al1, ar1, d1, h1, out1);
    k_l2prep<<<(NN + 255) / 256, 256, 0, stream>>>(out1, b1, W2, as2, ad2, h2, al2, ar2, d2, out2);
    k_denom2<<<(NTOT + 255) / 256, 256, 0, stream>>>(ei, al2, ar2, d2);
    k_agg2<<<(NTOT + 255) / 256, 256, 0, stream>>>(ei, al2, ar2, d2, h2, out2);
    k_final<<<(NN + 255) / 256, 256, 0, stream>>>(out2, b2, out);
}

// Round 2
// 676.055 us; speedup vs baseline: 6.4905x; 6.4905x over previous
//
#include <hip/hip_runtime.h>
#include <math.h>

#define NN 100000
#define NEDGE 1600000
#define NTOT 1700000          // edges + self loops
#define FIN 512
#define NH1 8
#define NC1 8
#define F1 64                 // NH1*NC1
#define NC2 10
#define SLOPE 0.2f
#define EPSF 1e-16f
#define SCAN_BLK 1024
#define NB ((NN + SCAN_BLK - 1) / SCAN_BLK)   // 98

__device__ __forceinline__ float lrelu(float x) { return x > 0.f ? x : SLOPE * x; }
__device__ __forceinline__ float eluf(float x) { return x > 0.f ? x : __expf(x) - 1.f; }

__device__ __forceinline__ int edge_dst(const int* __restrict__ ei, int e) {
    return (e < NEDGE) ? ei[NEDGE + e] : (e - NEDGE);
}
__device__ __forceinline__ int edge_src(const int* __restrict__ ei, int e) {
    return (e < NEDGE) ? ei[e] : (e - NEDGE);
}

// ---------------- GEMM1: h1[NN,64] = x[NN,512] @ W1[512,64] ----------------
#define BM 64
#define BK 32

__global__ __launch_bounds__(256) void k_gemm1(const float* __restrict__ x,
                                               const float* __restrict__ W,
                                               float* __restrict__ h1)
{
    __shared__ float As[BK][BM + 4];
    __shared__ float Bs[BK][F1 + 4];
    const int tid = threadIdx.x;
    const int row0 = blockIdx.x * BM;
    const int ti = tid >> 4, tj = tid & 15;
    float acc[4][4] = {};

    for (int k0 = 0; k0 < FIN; k0 += BK) {
        #pragma unroll
        for (int l = 0; l < 2; ++l) {
            int idx = tid + l * 256;
            int r = idx >> 3, c4 = idx & 7;
            int gr = row0 + r;
            float4 v = make_float4(0.f, 0.f, 0.f, 0.f);
            if (gr < NN) v = *(const float4*)(x + (size_t)gr * FIN + k0 + (c4 << 2));
            As[(c4 << 2) + 0][r] = v.x;
            As[(c4 << 2) + 1][r] = v.y;
            As[(c4 << 2) + 2][r] = v.z;
            As[(c4 << 2) + 3][r] = v.w;
        }
        #pragma unroll
        for (int l = 0; l < 2; ++l) {
            int idx = tid + l * 256;
            int r = idx >> 4, c4 = idx & 15;
            float4 v = *(const float4*)(W + (size_t)(k0 + r) * F1 + (c4 << 2));
            *(float4*)&Bs[r][c4 << 2] = v;
        }
        __syncthreads();
        #pragma unroll
        for (int kk = 0; kk < BK; ++kk) {
            float4 a = *(const float4*)&As[kk][ti << 2];
            float4 b = *(const float4*)&Bs[kk][tj << 2];
            acc[0][0] += a.x * b.x; acc[0][1] += a.x * b.y; acc[0][2] += a.x * b.z; acc[0][3] += a.x * b.w;
            acc[1][0] += a.y * b.x; acc[1][1] += a.y * b.y; acc[1][2] += a.y * b.z; acc[1][3] += a.y * b.w;
            acc[2][0] += a.z * b.x; acc[2][1] += a.z * b.y; acc[2][2] += a.z * b.z; acc[2][3] += a.z * b.w;
            acc[3][0] += a.w * b.x; acc[3][1] += a.w * b.y; acc[3][2] += a.w * b.z; acc[3][3] += a.w * b.w;
        }
        __syncthreads();
    }
    #pragma unroll
    for (int i = 0; i < 4; ++i) {
        int gr = row0 + (ti << 2) + i;
        if (gr < NN) {
            *(float4*)(h1 + (size_t)gr * F1 + (tj << 2)) =
                make_float4(acc[i][0], acc[i][1], acc[i][2], acc[i][3]);
        }
    }
}

// ---------------- prep1: al1/ar1 [NN,8] ----------------
__global__ void k_prep1(const float* __restrict__ h1,
                        const float* __restrict__ asrc, const float* __restrict__ adst,
                        float* __restrict__ al, float* __restrict__ ar)
{
    int i = blockIdx.x * blockDim.x + threadIdx.x;
    if (i >= NN * NH1) return;
    int node = i >> 3, hh = i & 7;
    const float* hp = h1 + (size_t)node * F1 + hh * NC1;
    float4 h0 = *(const float4*)hp;
    float4 h4 = *(const float4*)(hp + 4);
    const float* as = asrc + hh * NC1;
    const float* ad = adst + hh * NC1;
    float sa = h0.x * as[0] + h0.y * as[1] + h0.z * as[2] + h0.w * as[3]
             + h4.x * as[4] + h4.y * as[5] + h4.z * as[6] + h4.w * as[7];
    float sd = h0.x * ad[0] + h0.y * ad[1] + h0.z * ad[2] + h0.w * ad[3]
             + h4.x * ad[4] + h4.y * ad[5] + h4.z * ad[6] + h4.w * ad[7];
    al[i] = sa; ar[i] = sd;
}

// ---------------- CSR build ----------------
__global__ void k_zero(int* __restrict__ cnt)
{
    int i = blockIdx.x * blockDim.x + threadIdx.x;
    if (i < NN) cnt[i] = 0;
}

__global__ void k_hist(const int* __restrict__ ei, int* __restrict__ cnt)
{
    int e = blockIdx.x * blockDim.x + threadIdx.x;
    if (e >= NTOT) return;
    atomicAdd(&cnt[edge_dst(ei, e)], 1);
}

// block scans 1024 counts (256 thr x 4), writes exclusive offsets + block sum
__global__ __launch_bounds__(256) void k_scan1(const int* __restrict__ cnt,
                                               int* __restrict__ off,
                                               int* __restrict__ bsum)
{
    __shared__ int s[256];
    int t = threadIdx.x;
    int base = blockIdx.x * SCAN_BLK + t * 4;
    int c0 = (base + 0 < NN) ? cnt[base + 0] : 0;
    int c1 = (base + 1 < NN) ? cnt[base + 1] : 0;
    int c2 = (base + 2 < NN) ? cnt[base + 2] : 0;
    int c3 = (base + 3 < NN) ? cnt[base + 3] : 0;
    int ts = c0 + c1 + c2 + c3;
    s[t] = ts;
    __syncthreads();
    #pragma unroll
    for (int d = 1; d < 256; d <<= 1) {
        int v = (t >= d) ? s[t - d] : 0;
        __syncthreads();
        s[t] += v;
        __syncthreads();
    }
    int run = s[t] - ts;    // exclusive prefix of this thread's group
    if (t == 255) bsum[blockIdx.x] = s[255];
    if (base + 0 < NN) off[base + 0] = run; run += c0;
    if (base + 1 < NN) off[base + 1] = run; run += c1;
    if (base + 2 < NN) off[base + 2] = run; run += c2;
    if (base + 3 < NN) off[base + 3] = run;
}

__global__ void k_scan2(int* __restrict__ bsum, int* __restrict__ off)
{
    if (threadIdx.x == 0 && blockIdx.x == 0) {
        int run = 0;
        for (int b = 0; b < NB; ++b) { int v = bsum[b]; bsum[b] = run; run += v; }
        off[NN] = run;   // == NTOT
    }
}

// finalize offsets, re-zero cnt for reuse as fill counters
__global__ void k_scan3(int* __restrict__ off, const int* __restrict__ bsum,
                        int* __restrict__ cnt)
{
    int i = blockIdx.x * blockDim.x + threadIdx.x;
    if (i >= NN) return;
    off[i] += bsum[i >> 10];
    cnt[i] = 0;
}

__global__ void k_scatter(const int* __restrict__ ei, const int* __restrict__ off,
                          int* __restrict__ fill, int* __restrict__ esrc)
{
    int e = blockIdx.x * blockDim.x + threadIdx.x;
    if (e >= NTOT) return;
    int d = edge_dst(ei, e);
    int pos = atomicAdd(&fill[d], 1);
    esrc[off[d] + pos] = edge_src(ei, e);
}

// ------------- agg1: one wave per dst node; fused softmax-agg + bias + ELU -------------
__global__ __launch_bounds__(256) void k_agg1csr(const int* __restrict__ off,
                                                 const int* __restrict__ esrc,
                                                 const float* __restrict__ al,
                                                 const float* __restrict__ ar,
                                                 const float* __restrict__ h1,
                                                 const float* __restrict__ b1,
                                                 float* __restrict__ g)
{
    int node = blockIdx.x * 4 + (threadIdx.x >> 6);
    int lane = threadIdx.x & 63;
    int h = lane >> 3;
    int beg = off[node], end = off[node + 1];
    float arn = ar[node * NH1 + h];
    float acc0 = 0.f, acc1 = 0.f, ds0 = 0.f, ds1 = 0.f;
    int i = beg;
    for (; i + 1 < end; i += 2) {
        int s0 = esrc[i], s1 = esrc[i + 1];
        float e0 = __expf(lrelu(al[s0 * NH1 + h] + arn));
        float e1 = __expf(lrelu(al[s1 * NH1 + h] + arn));
        acc0 += h1[(size_t)s0 * F1 + lane] * e0; ds0 += e0;
        acc1 += h1[(size_t)s1 * F1 + lane] * e1; ds1 += e1;
    }
    if (i < end) {
        int s0 = esrc[i];
        float e0 = __expf(lrelu(al[s0 * NH1 + h] + arn));
        acc0 += h1[(size_t)s0 * F1 + lane] * e0; ds0 += e0;
    }
    float v = (acc0 + acc1) / (ds0 + ds1 + EPSF);
    g[(size_t)node * F1 + lane] = eluf(v + b1[lane]);
}

// ------------- l2prep: h2 = g @ W2 ; al2/ar2 -------------
__global__ __launch_bounds__(256) void k_l2prep(
    const float* __restrict__ g, const float* __restrict__ W2,
    const float* __restrict__ asrc2, const float* __restrict__ adst2,
    float* __restrict__ h2, float* __restrict__ al2, float* __restrict__ ar2)
{
    __shared__ float sW[F1 * NC2];
    __shared__ float sas[NC2], sad[NC2];
    int tid = threadIdx.x;
    for (int i = tid; i < F1 * NC2; i += 256) sW[i] = W2[i];
    if (tid < NC2) { sas[tid] = asrc2[tid]; sad[tid] = adst2[tid]; }
    __syncthreads();
    int n = blockIdx.x * 256 + tid;
    if (n >= NN) return;

    const float* row = g + (size_t)n * F1;
    float acc[NC2] = {};
    #pragma unroll
    for (int c = 0; c < F1; c += 4) {
        float4 v = *(const float4*)(row + c);
        #pragma unroll
        for (int o = 0; o < NC2; ++o) {
            acc[o] += v.x * sW[(c + 0) * NC2 + o] + v.y * sW[(c + 1) * NC2 + o]
                    + v.z * sW[(c + 2) * NC2 + o] + v.w * sW[(c + 3) * NC2 + o];
        }
    }
    float sa = 0.f, sd = 0.f;
    #pragma unroll
    for (int o = 0; o < NC2; ++o) { sa += acc[o] * sas[o]; sd += acc[o] * sad[o]; }
    al2[n] = sa; ar2[n] = sd;
    float* h2p = h2 + (size_t)n * NC2;
    #pragma unroll
    for (int o = 0; o < NC2; ++o) h2p[o] = acc[o];
}

// ------------- agg2: 16-lane group per node; fused bias + log_softmax -------------
__global__ __launch_bounds__(256) void k_agg2csr(const int* __restrict__ off,
                                                 const int* __restrict__ esrc,
                                                 const float* __restrict__ al2,
                                                 const float* __restrict__ ar2,
                                                 const float* __restrict__ h2,
                                                 const float* __restrict__ b2,
                                                 float* __restrict__ out)
{
    int node = blockIdx.x * 16 + (threadIdx.x >> 4);
    int li = threadIdx.x & 15;
    int beg = off[node], end = off[node + 1];
    float arn = ar2[node];
    float acc = 0.f, dsum = 0.f;
    for (int i = beg; i < end; ++i) {
        int s = esrc[i];
        float ev = __expf(lrelu(al2[s] + arn));
        if (li < NC2) acc += h2[(size_t)s * NC2 + li] * ev;
        dsum += ev;
    }
    float z = (li < NC2) ? acc / (dsum + EPSF) + b2[li] : -1e30f;
    float m = z;
    #pragma unroll
    for (int d = 8; d >= 1; d >>= 1) m = fmaxf(m, __shfl_xor(m, d, 16));
    float ex = (li < NC2) ? __expf(z - m) : 0.f;
    float ss = ex;
    #pragma unroll
    for (int d = 8; d >= 1; d >>= 1) ss += __shfl_xor(ss, d, 16);
    float ls = __logf(ss) + m;
    if (li < NC2) out[(size_t)node * NC2 + li] = z - ls;
}

extern "C" void kernel_launch(void* const* d_in, const int* in_sizes, int n_in,
                              void* d_out, int out_size, void* d_ws, size_t ws_size,
                              hipStream_t stream)
{
    const float* x    = (const float*)d_in[0];
    const int*   ei   = (const int*)d_in[1];
    const float* W1   = (const float*)d_in[2];
    const float* as1  = (const float*)d_in[3];
    const float* ad1  = (const float*)d_in[4];
    const float* b1   = (const float*)d_in[5];
    const float* W2   = (const float*)d_in[6];
    const float* as2  = (const float*)d_in[7];
    const float* ad2  = (const float*)d_in[8];
    const float* b2   = (const float*)d_in[9];
    float* out = (float*)d_out;

    float* ws  = (float*)d_ws;
    float* h1  = ws;                           // NN*64
    float* al1 = h1 + (size_t)NN * F1;         // NN*8
    float* ar1 = al1 + (size_t)NN * NH1;       // NN*8
    float* g   = ar1 + (size_t)NN * NH1;       // NN*64
    int* cnt   = (int*)(g + (size_t)NN * F1);  // NN      (reused as fill)
    int* off   = cnt + NN;                     // NN+1
    int* bsum  = off + NN + 1;                 // NB (pad 128)
    int* esrc  = bsum + 128;                   // NTOT
    // layer-2 buffers alias h1 (dead after k_agg1csr)
    float* h2  = h1;                           // NN*10
    float* al2 = h1 + (size_t)NN * NC2;        // NN
    float* ar2 = al2 + NN;                     // NN

    k_gemm1<<<(NN + BM - 1) / BM, 256, 0, stream>>>(x, W1, h1);
    k_prep1<<<(NN * NH1 + 255) / 256, 256, 0, stream>>>(h1, as1, ad1, al1, ar1);
    k_zero<<<(NN + 255) / 256, 256, 0, stream>>>(cnt);
    k_hist<<<(NTOT + 255) / 256, 256, 0, stream>>>(ei, cnt);
    k_scan1<<<NB, 256, 0, stream>>>(cnt, off, bsum);
    k_scan2<<<1, 64, 0, stream>>>(bsum, off);
    k_scan3<<<(NN + 255) / 256, 256, 0, stream>>>(off, bsum, cnt);
    k_scatter<<<(NTOT + 255) / 256, 256, 0, stream>>>(ei, off, cnt, esrc);
    k_agg1csr<<<NN / 4, 256, 0, stream>>>(off, esrc, al1, ar1, h1, b1, g);
    k_l2prep<<<(NN + 255) / 256, 256, 0, stream>>>(g, W2, as2, ad2, h2, al2, ar2);
    k_agg2csr<<<NN / 16, 256, 0, stream>>>(off, esrc, al2, ar2, h2, b2, out);
}